// Round 26
// baseline (662.746 us; speedup 1.0000x reference)
//
#include <hip/hip_runtime.h>
#include <cstdio>

typedef unsigned short u16;
typedef __attribute__((ext_vector_type(4))) float f32x4;
typedef __attribute__((ext_vector_type(8))) short s16x8;
typedef __attribute__((ext_vector_type(4))) unsigned short u16x4;

#define DEV static __device__ __forceinline__

DEV float bf2f(u16 u) { union { unsigned int i; float f; } v; v.i = ((unsigned int)u) << 16; return v.f; }
DEV u16 f2bf(float f) {
  unsigned int x = __float_as_uint(f);
  unsigned int r = (x + 0x7fffu + ((x >> 16) & 1u)) >> 16;
  return (u16)r;
}

typedef const __attribute__((address_space(1))) unsigned int* gptr_t;
typedef __attribute__((address_space(3))) unsigned int* lptr_t;
DEV void gl16(const u16* g, u16* l) {
  __builtin_amdgcn_global_load_lds((gptr_t)g, (lptr_t)l, 16, 0, 0);
}

// XCD-aware chunked block swizzle (requires total blocks % 8 == 0).
DEV void xcd_swz(int& x, int& y, int& z) {
  const int gx = gridDim.x, gy = gridDim.y;
  const int gid = (int)blockIdx.x + gx * ((int)blockIdx.y + gy * (int)blockIdx.z);
  const int cpx = (gx * gy * (int)gridDim.z) >> 3;
  const int sw = (gid & 7) * cpx + (gid >> 3);
  x = sw % gx;
  const int rem = sw / gx;
  y = rem % gy;
  z = rem / gy;
}

// ---------------------------------------------------------------------------
// Prologue zero: all zero-init jobs in one grid-stride kernel.
// ---------------------------------------------------------------------------
DEV void border_pix(int e, int P, int& py, int& px) {
  if (e < P) { py = 0; px = e; }
  else if (e < 2 * P) { py = P - 1; px = e - P; }
  else { int j = e - 2 * P; py = 1 + (j >> 1); px = (j & 1) ? P - 1 : 0; }
}

__global__ __launch_bounds__(256) void prologue_zero(u16* __restrict__ x1,
    u16* __restrict__ x2, u16* __restrict__ x3, u16* __restrict__ mscu)
{
  const long Z1 = 2720000;           // x1 full
  const long Z2 = Z1 + 576240;       // x2 chpad (P=98, 30 ch)
  const long Z3 = Z2 + 223488;       // x2 border (NB=388, 288 ch)
  const long Z4 = Z3 + 2258160;      // x3 chpad (P=194, 30 ch)
  const long Z5 = Z4 + 444672;       // x3 border (NB=772, 288 ch)
  const long Z6 = Z5 + 36864;        // msc as u16
  long i = (long)blockIdx.x * 256 + threadIdx.x;
  const long stride = (long)gridDim.x * 256;
  for (; i < Z6; i += stride) {
    if (i < Z1) {
      x1[i] = 0;
    } else if (i < Z2) {
      long j = i - Z1;
      long pix = j / 30; int c = (int)(j - pix * 30);
      x2[pix * 288 + 258 + c] = 0;
    } else if (i < Z3) {
      long j = i - Z2;
      const int NB = 388;
      long bp = j / 288; int c = (int)(j - bp * 288);
      int b = (int)(bp / NB), e = (int)(bp - (long)b * NB);
      int py, px; border_pix(e, 98, py, px);
      x2[((size_t)b * 9604 + (size_t)py * 98 + px) * 288 + c] = 0;
    } else if (i < Z4) {
      long j = i - Z3;
      long pix = j / 30; int c = (int)(j - pix * 30);
      x3[pix * 288 + 258 + c] = 0;
    } else if (i < Z5) {
      long j = i - Z4;
      const int NB = 772;
      long bp = j / 288; int c = (int)(j - bp * 288);
      int b = (int)(bp / NB), e = (int)(bp - (long)b * NB);
      int py, px; border_pix(e, 194, py, px);
      x3[((size_t)b * 37636 + (size_t)py * 194 + px) * 288 + c] = 0;
    } else {
      mscu[i - Z5] = 0;
    }
  }
}

// ---------------------------------------------------------------------------
// Prologue repack: all weight conversions in one grid-stride kernel.
// ---------------------------------------------------------------------------
DEV u16 dec_repack_elem(const float* w, int j, int S, int KSZ) {
  int m = j >> 10, k = j & 1023;
  int oc = m & 1, ph = m >> 1;
  int tap = k >> 8, ic = k & 255;
  int dy = tap >> 1, dx = tap & 1;
  float val = 0.0f;
  if (ph < S * S) {
    int ry = ph / S, rx = ph % S;
    int ky = ry + S * dy, kx = rx + S * dx;
    if (ky < KSZ && kx < KSZ)
      val = w[((size_t)(ic * 2 + oc) * KSZ + ky) * KSZ + kx];
  }
  return f2bf(val);
}

DEV u16 blend_repack_elem(const float* w, long j, int IC, int ICp) {
  int ic = (int)(j % ICp);
  int oc = (int)((j / ICp) % 256);
  int tap = (int)(j / ((long)ICp * 256));
  return (ic < IC) ? f2bf(w[((size_t)oc * IC + ic) * 9 + tap]) : (u16)0;
}

__global__ __launch_bounds__(256) void prologue_repack(
    const float* __restrict__ wb1, const float* __restrict__ wb2,
    const float* __restrict__ wb3, const float* __restrict__ wd1,
    const float* __restrict__ wd2, const float* __restrict__ wd3,
    const float* __restrict__ wc1, const float* __restrict__ wc2,
    const float* __restrict__ wc3,
    u16* __restrict__ wr1, u16* __restrict__ wr2, u16* __restrict__ wr3,
    u16* __restrict__ wd1r, u16* __restrict__ wd2r, u16* __restrict__ wd3r,
    u16* __restrict__ wc1b, u16* __restrict__ wc2b, u16* __restrict__ wc3b)
{
  const long N1 = 1253376;          // wr1 (544)
  const long N2 = N1 + 663552;      // wr2 (288)
  const long N3 = N2 + 663552;      // wr3 (288)
  const long N4 = N3 + 16384;       // wd1r
  const long N5 = N4 + 16384;       // wd2r
  const long N6 = N5 + 32768;       // wd3r
  const long N7 = N6 + 262144;      // wc1b
  const long N8 = N7 + 131072;      // wc2b
  const long N9 = N8 + 65536;       // wc3b
  long i = (long)blockIdx.x * 256 + threadIdx.x;
  const long stride = (long)gridDim.x * 256;
  for (; i < N9; i += stride) {
    if (i < N1) {
      wr1[i] = blend_repack_elem(wb1, i, 516, 544);
    } else if (i < N2) {
      long j = i - N1; wr2[j] = blend_repack_elem(wb2, j, 258, 288);
    } else if (i < N3) {
      long j = i - N2; wr3[j] = blend_repack_elem(wb3, j, 258, 288);
    } else if (i < N4) {
      int j = (int)(i - N3); wd1r[j] = dec_repack_elem(wd1, j, 2, 4);
    } else if (i < N5) {
      int j = (int)(i - N4); wd2r[j] = dec_repack_elem(wd2, j, 2, 4);
    } else if (i < N6) {
      int j = (int)(i - N5); wd3r[j] = dec_repack_elem(wd3, j, 4, 6);
    } else if (i < N7) {
      long j = i - N6; wc1b[j] = f2bf(wc1[j]);
    } else if (i < N8) {
      long j = i - N7; wc2b[j] = f2bf(wc2[j]);
    } else {
      long j = i - N8; wc3b[j] = f2bf(wc3[j]);
    }
  }
}

// ---------------------------------------------------------------------------
// key transpose x3: fp32 [B][512][2304] -> bf16 [B][2304][512].
// ---------------------------------------------------------------------------
__global__ __launch_bounds__(256) void trans_key3(const float* __restrict__ k0,
    const float* __restrict__ k1, const float* __restrict__ k2,
    u16* __restrict__ y0, u16* __restrict__ y1, u16* __restrict__ y2)
{
  __shared__ u16 t[64][72];
  const int tid = threadIdx.x;
  const int z = blockIdx.z;
  const float* X = (z < 2) ? k0 : (z < 4) ? k1 : k2;
  u16* Y = (z < 2) ? y0 : (z < 4) ? y1 : y2;
  const int b = z & 1;
  const int n0 = blockIdx.x * 64, k0i = blockIdx.y * 64;
  const float* Xb = X + (size_t)b * 512 * 2304;
  const int nl = tid & 63, kr = tid >> 6;
#pragma unroll
  for (int kk = 0; kk < 16; ++kk) {
    int kl = kr + kk * 4;
    t[kl][nl] = f2bf(Xb[(size_t)(k0i + kl) * 2304 + n0 + nl]);
  }
  __syncthreads();
  const int nr = tid >> 2, kb = (tid & 3) * 16;
  u16* yp = Y + (size_t)b * 2304 * 512 + (size_t)(n0 + nr) * 512 + k0i + kb;
#pragma unroll
  for (int i = 0; i < 4; ++i) {
    u16x4 v;
#pragma unroll
    for (int e = 0; e < 4; ++e) v[e] = t[kb + i * 4 + e][nr];
    *(u16x4*)&yp[i * 4] = v;
  }
}

// ---------------------------------------------------------------------------
// Both similarity GEMMs in one launch. 128x128 tile, BK=64 pairs, gload_lds.
// grid (18,18,4) = 1296 blocks (%8==0) -> XCD swizzle applied.
// ---------------------------------------------------------------------------
__global__ __launch_bounds__(256) void sim_gemm_pair2(const u16* __restrict__ ikT,
    const u16* __restrict__ pkT, const u16* __restrict__ keyT,
    u16* __restrict__ simG, u16* __restrict__ simL)
{
  __shared__ alignas(16) u16 Al[2][2][8][64][8];
  __shared__ alignas(16) u16 Bl[2][2][8][64][8];
  const int tid = threadIdx.x;
  const int lane = tid & 63, wv = tid >> 6;
  const int fr = lane & 15, kq = lane >> 4;
  const int wr = wv >> 1, wc = wv & 1;
  int bx, by, z;
  xcd_swz(bx, by, z);
  const u16* AT = (z < 2) ? ikT : pkT;
  u16* out = (z < 2) ? simG : simL;
  const int b = z & 1;
  const int n0 = bx * 128, m0 = by * 128;
  const u16* Ab = AT + (size_t)b * 2304 * 512;
  const u16* Bb = keyT + (size_t)b * 2304 * 512;
  const int ar0 = m0 + wv * 16 + fr, ar1 = m0 + (wv + 4) * 16 + fr;
  const int br0 = n0 + wv * 16 + fr, br1 = n0 + (wv + 4) * 16 + fr;
  f32x4 acc[4][4];
#pragma unroll
  for (int p = 0; p < 4; ++p)
#pragma unroll
    for (int j = 0; j < 4; ++j) acc[p][j] = (f32x4){0, 0, 0, 0};
  auto ISSUE = [&](int buf, int sp) {
#pragma unroll
    for (int h = 0; h < 2; ++h) {
      const int k0 = (sp * 2 + h) * 32 + kq * 8;
      gl16(&Ab[(size_t)ar0 * 512 + k0], &Al[buf][h][wv][0][0]);
      gl16(&Ab[(size_t)ar1 * 512 + k0], &Al[buf][h][wv + 4][0][0]);
      gl16(&Bb[(size_t)br0 * 512 + k0], &Bl[buf][h][wv][0][0]);
      gl16(&Bb[(size_t)br1 * 512 + k0], &Bl[buf][h][wv + 4][0][0]);
    }
  };
  ISSUE(0, 0);
  __syncthreads();
  const int NPAIR = 512 / 64;
  for (int sp = 0; sp < NPAIR; ++sp) {
    const int cur = sp & 1;
    if (sp + 1 < NPAIR) ISSUE(cur ^ 1, sp + 1);
#pragma unroll
    for (int h = 0; h < 2; ++h) {
      s16x8 bf[4], af[4];
#pragma unroll
      for (int j = 0; j < 4; ++j) bf[j] = *(const s16x8*)&Bl[cur][h][wc * 4 + j][lane][0];
#pragma unroll
      for (int p = 0; p < 4; ++p) af[p] = *(const s16x8*)&Al[cur][h][wr * 4 + p][lane][0];
#pragma unroll
      for (int p = 0; p < 4; ++p)
#pragma unroll
        for (int j = 0; j < 4; ++j)
          acc[p][j] = __builtin_amdgcn_mfma_f32_16x16x32_bf16(af[p], bf[j], acc[p][j], 0, 0, 0);
    }
    __syncthreads();
  }
  const int col = lane & 15, rg = (lane >> 4) * 4;
#pragma unroll
  for (int p = 0; p < 4; ++p)
#pragma unroll
    for (int j = 0; j < 4; ++j)
#pragma unroll
      for (int r = 0; r < 4; ++r) {
        int pr = m0 + (wr * 4 + p) * 16 + rg + r;
        int q = n0 + (wc * 4 + j) * 16 + col;
        out[((size_t)b * 2304 + pr) * 2304 + q] = f2bf((acc[p][j][r] + 1.0f) * 0.5f);
      }
}

// ---------------------------------------------------------------------------
// Per-row stats of local_sim (bf16): cut = 4th-largest over q, mn = min.
// ---------------------------------------------------------------------------
__global__ __launch_bounds__(256) void rowstats(const u16* __restrict__ simL,
    float* __restrict__ cutv, float* __restrict__ mnv)
{
  const int row = blockIdx.x;
  const int tid = threadIdx.x;
  const u16* r = simL + (size_t)row * 2304;
  float t0 = -1e30f, t1 = -1e30f, t2 = -1e30f, t3 = -1e30f, mn = 1e30f;
  for (int i = tid; i < 2304; i += 256) {
    float v = bf2f(r[i]);
    mn = fminf(mn, v);
    if (v > t3) {
      if (v > t2) { t3 = t2; if (v > t1) { t2 = t1; if (v > t0) { t1 = t0; t0 = v; } else t1 = v; } else t2 = v; }
      else t3 = v;
    }
  }
  __shared__ float s4[256][4];
  __shared__ float smv[256];
  s4[tid][0] = t0; s4[tid][1] = t1; s4[tid][2] = t2; s4[tid][3] = t3;
  smv[tid] = mn;
  __syncthreads();
  for (int s = 128; s > 0; s >>= 1) {
    if (tid < s) {
      float a0 = s4[tid][0], a1 = s4[tid][1], a2 = s4[tid][2], a3 = s4[tid][3];
      float b0 = s4[tid + s][0], b1 = s4[tid + s][1], b2 = s4[tid + s][2], b3 = s4[tid + s][3];
      float m0 = fmaxf(a0, b3), m1 = fmaxf(a1, b2), m2 = fmaxf(a2, b1), m3 = fmaxf(a3, b0);
      float c0 = fmaxf(m0, m2), c2 = fminf(m0, m2), c1 = fmaxf(m1, m3), c3 = fminf(m1, m3);
      s4[tid][0] = fmaxf(c0, c1); s4[tid][1] = fminf(c0, c1);
      s4[tid][2] = fmaxf(c2, c3); s4[tid][3] = fminf(c2, c3);
      smv[tid] = fminf(smv[tid], smv[tid + s]);
    }
    __syncthreads();
  }
  if (tid == 0) { cutv[row] = s4[0][3]; mnv[row] = smv[0]; }
}

// ---------------------------------------------------------------------------
// Both score passes in one launch. grid (9,18,4).
// ---------------------------------------------------------------------------
__global__ __launch_bounds__(256) void score_both(const u16* __restrict__ simG,
    const u16* __restrict__ simL, const float* __restrict__ init_seg,
    const float* __restrict__ prev_seg, const float* __restrict__ cutv,
    const float* __restrict__ mnv, float* __restrict__ msc)
{
  const int z = blockIdx.z;
  const bool loc = (z >= 2);
  const int b = z & 1;
  const u16* sim = loc ? simL : simG;
  const float* seg = loc ? prev_seg : init_seg;
  const int chBase = loc ? 2 : 0;
  const int q = blockIdx.x * 256 + threadIdx.x;
  const int p0 = blockIdx.y * 128;
  const u16* sp = sim + ((size_t)b * 2304 + p0) * 2304 + q;
  const float* sg = seg + (size_t)b * 2 * 2304;
  const float* cu = cutv + (size_t)b * 2304 + p0;
  const float* ml = mnv + (size_t)b * 2304 + p0;
  float m0 = 0.0f, m1 = 0.0f;
  if (loc) {
    for (int p = 0; p < 128; ++p) {
      float sv = bf2f(sp[(size_t)p * 2304]);
      float cut = cu[p], mnr = ml[p];
      float mv = (sv < cut) ? mnr : sv;
      float s0 = sg[p0 + p];
      float s1 = sg[2304 + p0 + p];
      m0 = fmaxf(m0, mv * s0);
      m1 = fmaxf(m1, mv * s1);
    }
  } else {
    for (int p = 0; p < 128; ++p) {
      float sv = bf2f(sp[(size_t)p * 2304]);
      float s0 = sg[p0 + p];
      float s1 = sg[2304 + p0 + p];
      m0 = fmaxf(m0, sv * s0);
      m1 = fmaxf(m1, sv * s1);
    }
  }
  atomicMax((int*)&msc[((size_t)b * 4 + chBase) * 2304 + q], __float_as_int(m0));
  atomicMax((int*)&msc[((size_t)b * 4 + chBase + 1) * 2304 + q], __float_as_int(m1));
}

// ---------------------------------------------------------------------------
// fill_scores + copy_mask merged: flat grid-stride.
// ---------------------------------------------------------------------------
__global__ __launch_bounds__(256) void fillmask(const float* __restrict__ msc,
    const float* __restrict__ mask, u16* __restrict__ x1)
{
  const long NSC = 2 * 2304;
  const long NMK = NSC + (long)2 * 256 * 2304;
  long i = (long)blockIdx.x * 256 + threadIdx.x;
  const long stride = (long)gridDim.x * 256;
  for (; i < NMK; i += stride) {
    if (i < NSC) {
      int idx = (int)i;
      int b = idx / 2304, q = idx % 2304;
      int py = q / 48, px = q % 48;
      u16x4 v;
#pragma unroll
      for (int c = 0; c < 4; ++c) v[c] = f2bf(msc[((size_t)b * 4 + c) * 2304 + q]);
      *(u16x4*)&x1[((size_t)b * 2500 + (py + 1) * 50 + px + 1) * 544 + 256] = v;
    } else {
      long j = i - NSC;
      int b = (int)(j / (256 * 2304));
      int r = (int)(j - (long)b * 256 * 2304);
      int c = r / 2304, q = r % 2304;
      int py = q / 48, px = q % 48;
      x1[((size_t)b * 2500 + (py + 1) * 50 + px + 1) * 544 + 260 + c] = f2bf(mask[j]);
    }
  }
}

// ---------------------------------------------------------------------------
// 1x1 conv: A (bf16 weights) via gload_lds, B (fp32 NCHW X) reg-converted.
// BK=64 pairs. grid (NBLK, MBLK, B), %8==0 -> XCD swizzle.
// ---------------------------------------------------------------------------
template<int MB>
__global__ __launch_bounds__(256) void conv1x1_bk64(const float* __restrict__ X,
    const u16* __restrict__ Wb, const float* __restrict__ bias,
    u16* __restrict__ Y, int K, int WD, int Cp)
{
  const int N = WD * WD;
  const int P = WD + 2, HWp = P * P;
  constexpr int SUB = MB / 16, SPW = SUB / 4;
  __shared__ alignas(16) u16 Al[2][2][SUB][64][8];
  __shared__ alignas(16) u16 Bl[2][2][4][64][8];
  const int tid = threadIdx.x;
  int bx, by, bz;
  xcd_swz(bx, by, bz);
  const int n0 = bx * 64, m0 = by * MB, b = bz;
  const int lane = tid & 63, wv = tid >> 6;
  const int fr = lane & 15, kq = lane >> 4;
  const float* Xb = X + (size_t)b * K * N;
  const int bpix = n0 + wv * 16 + fr;
  f32x4 acc[SPW][4];
#pragma unroll
  for (int p = 0; p < SPW; ++p)
#pragma unroll
    for (int j = 0; j < 4; ++j) acc[p][j] = (f32x4){0, 0, 0, 0};
  s16x8 bN[2];
  auto ISSUEA = [&](int buf, int sp) {
#pragma unroll
    for (int h = 0; h < 2; ++h) {
      const int k0 = (sp * 2 + h) * 32 + kq * 8;
#pragma unroll
      for (int p = 0; p < SPW; ++p)
        gl16(&Wb[(size_t)(m0 + (wv * SPW + p) * 16 + fr) * K + k0],
             &Al[buf][h][wv * SPW + p][0][0]);
    }
  };
  auto LDB = [&](int sp) {
#pragma unroll
    for (int h = 0; h < 2; ++h) {
      const int k0 = (sp * 2 + h) * 32;
#pragma unroll
      for (int i = 0; i < 8; ++i)
        bN[h][i] = (short)f2bf(Xb[(size_t)(k0 + kq * 8 + i) * N + bpix]);
    }
  };
  auto STB = [&](int buf) {
#pragma unroll
    for (int h = 0; h < 2; ++h) *(s16x8*)&Bl[buf][h][wv][lane][0] = bN[h];
  };
  ISSUEA(0, 0); LDB(0); STB(0);
  __syncthreads();
  const int NPAIR = K / 64;
  for (int sp = 0; sp < NPAIR; ++sp) {
    const int cur = sp & 1;
    const bool more = (sp + 1) < NPAIR;
    if (more) { ISSUEA(cur ^ 1, sp + 1); LDB(sp + 1); }
#pragma unroll
    for (int h = 0; h < 2; ++h) {
      s16x8 bf[4];
#pragma unroll
      for (int j = 0; j < 4; ++j) bf[j] = *(const s16x8*)&Bl[cur][h][j][lane][0];
#pragma unroll
      for (int p = 0; p < SPW; ++p) {
        s16x8 af = *(const s16x8*)&Al[cur][h][wv * SPW + p][lane][0];
#pragma unroll
        for (int j = 0; j < 4; ++j)
          acc[p][j] = __builtin_amdgcn_mfma_f32_16x16x32_bf16(af, bf[j], acc[p][j], 0, 0, 0);
      }
    }
    if (more) STB(cur ^ 1);
    __syncthreads();
  }
  const int col = lane & 15, rg = (lane >> 4) * 4;
#pragma unroll
  for (int j = 0; j < 4; ++j) {
    const int nn = n0 + j * 16 + col;
    const int py = nn / WD, px = nn % WD;
    const size_t rowb = ((size_t)b * HWp + (py + 1) * P + px + 1) * Cp;
#pragma unroll
    for (int p = 0; p < SPW; ++p) {
      const int oc0 = m0 + (wv * SPW + p) * 16 + rg;
      u16x4 v;
#pragma unroll
      for (int r = 0; r < 4; ++r)
        v[r] = f2bf(fmaxf(acc[p][j][r] + bias[oc0 + r], 0.0f));
      *(u16x4*)&Y[rowb + oc0] = v;
    }
  }
}

// ---------------------------------------------------------------------------
// MERGED: conv1x1 + deconv s=2 (bf16 out) in one launch, XCD swizzled
// (bijective over the full grid; role decided from swizzled bx).
// ---------------------------------------------------------------------------
template<int MB, int DWIN>
__global__ __launch_bounds__(256) void conv1x1_dec(const float* __restrict__ X,
    const u16* __restrict__ Wb, const float* __restrict__ bias,
    u16* __restrict__ Y, int K, int WD, int Cp,
    const u16* __restrict__ DX, const u16* __restrict__ DWr,
    const float* __restrict__ Dbias, u16* __restrict__ DY, int NCONVX)
{
  constexpr int SUB = MB / 16, SPW = SUB / 4;
  __shared__ alignas(16) u16 Al[2][2][SUB][64][8];
  __shared__ alignas(16) u16 Bl[2][2][4][64][8];
  const int tid = threadIdx.x;
  const int lane = tid & 63, wv = tid >> 6;
  const int fr = lane & 15, kq = lane >> 4;
  int bx, by, bz;
  xcd_swz(bx, by, bz);
  const int b = bz;
  if (bx >= NCONVX) {
    // ---- deconv path (S=2, MT=1, bf16 out into DY ch 256..257 of Cp) ----
    if (by != 0) return;
    constexpr int NP1 = DWIN + 1;
    constexpr int Np = NP1 * NP1;
    constexpr int WO = 2 * DWIN;
    constexpr int HWin = DWIN * DWIN;
    constexpr int Pout = WO + 2;
    constexpr int HWpo = Pout * Pout;
    const int n0 = (bx - NCONVX) * 64;
    const u16* Xb = DX + (size_t)b * HWin * 256 + kq * 8;
    const int pixn = n0 + wv * 16 + fr;
    const int t_y = pixn / NP1, t_x = pixn % NP1;
    f32x4 acc = {0, 0, 0, 0};
#pragma unroll
    for (int tap = 0; tap < 4; ++tap) {
      const int dy = tap >> 1, dx = tap & 1;
      const int iy = t_y - dy, ix = t_x - dx;
      const bool vsp = (pixn < Np) && ((unsigned)iy < (unsigned)DWIN) && ((unsigned)ix < (unsigned)DWIN);
      const u16* bpt = Xb + (size_t)(vsp ? iy * DWIN + ix : 0) * 256;
      for (int kk = 0; kk < 256; kk += 32) {
        s16x8 bf = *(const s16x8*)(bpt + kk);
        if (!vsp) {
#pragma unroll
          for (int i = 0; i < 8; ++i) bf[i] = 0;
        }
        s16x8 af = *(const s16x8*)&DWr[(size_t)fr * 1024 + tap * 256 + kk + kq * 8];
        acc = __builtin_amdgcn_mfma_f32_16x16x32_bf16(af, bf, acc, 0, 0, 0);
      }
    }
    const int col = lane & 15, rg = (lane >> 4) * 4;
    const int nn = n0 + wv * 16 + col;
    if (nn >= Np) return;
    const int oty = nn / NP1, otx = nn % NP1;
#pragma unroll
    for (int r = 0; r < 4; ++r) {
      int m = rg + r;
      int ph = m >> 1, oc = m & 1;
      if (ph >= 4) continue;
      int ry = ph >> 1, rx = ph & 1;
      int oy = 2 * oty + ry - 1, ox = 2 * otx + rx - 1;
      if ((unsigned)oy >= (unsigned)WO || (unsigned)ox >= (unsigned)WO) continue;
      float v = acc[r] + Dbias[oc];
      DY[((size_t)b * HWpo + (oy + 1) * Pout + ox + 1) * Cp + 256 + oc] = f2bf(v);
    }
    return;
  }
  // ---- conv path (identical to conv1x1_bk64) ----
  const int N = WD * WD;
  const int P = WD + 2, HWp = P * P;
  const int n0 = bx * 64, m0 = by * MB;
  const float* Xb = X + (size_t)b * K * N;
  const int bpix = n0 + wv * 16 + fr;
  f32x4 acc[SPW][4];
#pragma unroll
  for (int p = 0; p < SPW; ++p)
#pragma unroll
    for (int j = 0; j < 4; ++j) acc[p][j] = (f32x4){0, 0, 0, 0};
  s16x8 bN[2];
  auto ISSUEA = [&](int buf, int sp) {
#pragma unroll
    for (int h = 0; h < 2; ++h) {
      const int k0 = (sp * 2 + h) * 32 + kq * 8;
#pragma unroll
      for (int p = 0; p < SPW; ++p)
        gl16(&Wb[(size_t)(m0 + (wv * SPW + p) * 16 + fr) * K + k0],
             &Al[buf][h][wv * SPW + p][0][0]);
    }
  };
  auto LDB = [&](int sp) {
#pragma unroll
    for (int h = 0; h < 2; ++h) {
      const int k0 = (sp * 2 + h) * 32;
#pragma unroll
      for (int i = 0; i < 8; ++i)
        bN[h][i] = (short)f2bf(Xb[(size_t)(k0 + kq * 8 + i) * N + bpix]);
    }
  };
  auto STB = [&](int buf) {
#pragma unroll
    for (int h = 0; h < 2; ++h) *(s16x8*)&Bl[buf][h][wv][lane][0] = bN[h];
  };
  ISSUEA(0, 0); LDB(0); STB(0);
  __syncthreads();
  const int NPAIR = K / 64;
  for (int sp = 0; sp < NPAIR; ++sp) {
    const int cur = sp & 1;
    const bool more = (sp + 1) < NPAIR;
    if (more) { ISSUEA(cur ^ 1, sp + 1); LDB(sp + 1); }
#pragma unroll
    for (int h = 0; h < 2; ++h) {
      s16x8 bf[4];
#pragma unroll
      for (int j = 0; j < 4; ++j) bf[j] = *(const s16x8*)&Bl[cur][h][j][lane][0];
#pragma unroll
      for (int p = 0; p < SPW; ++p) {
        s16x8 af = *(const s16x8*)&Al[cur][h][wv * SPW + p][lane][0];
#pragma unroll
        for (int j = 0; j < 4; ++j)
          acc[p][j] = __builtin_amdgcn_mfma_f32_16x16x32_bf16(af, bf[j], acc[p][j], 0, 0, 0);
      }
    }
    if (more) STB(cur ^ 1);
    __syncthreads();
  }
  const int col = lane & 15, rg = (lane >> 4) * 4;
#pragma unroll
  for (int j = 0; j < 4; ++j) {
    const int nn = n0 + j * 16 + col;
    const int py = nn / WD, px = nn % WD;
    const size_t rowb = ((size_t)b * HWp + (py + 1) * P + px + 1) * Cp;
#pragma unroll
    for (int p = 0; p < SPW; ++p) {
      const int oc0 = m0 + (wv * SPW + p) * 16 + rg;
      u16x4 v;
#pragma unroll
      for (int r = 0; r < 4; ++r)
        v[r] = f2bf(fmaxf(acc[p][j][r] + bias[oc0 + r], 0.0f));
      *(u16x4*)&Y[rowb + oc0] = v;
    }
  }
}

// ---------------------------------------------------------------------------
// 3x3 conv pad1 + relu, MB x 64 tile, BK=64 pairs, gload_lds, XCD swizzle.
// ICP now a template constant: all /KS and *ICP fold to mul-shift (VALU cut).
// ---------------------------------------------------------------------------
template<int WD, int MB, int ICP>
__global__ __launch_bounds__(256) void blend3x3_bk64(const u16* __restrict__ X,
    const u16* __restrict__ Wr, const float* __restrict__ bias,
    u16* __restrict__ Y)
{
  constexpr int P = WD + 2, HWp = P * P, HW = WD * WD;
  constexpr int SUB = MB / 16, SPW = SUB / 4;
  constexpr int KS = ICP / 32, NS = 9 * KS;
  constexpr int NPAIR = (NS + 1) / 2;
  __shared__ alignas(16) u16 Al[2][2][SUB][64][8];
  __shared__ alignas(16) u16 Bl[2][2][4][64][8];
  const int tid = threadIdx.x;
  const int lane = tid & 63, wv = tid >> 6;
  const int fr = lane & 15, kq = lane >> 4;
  int bx, by, bz;
  xcd_swz(bx, by, bz);
  const int n0 = bx * 64, m0 = by * MB, b = bz;
  const u16* Xb = X + (size_t)b * HWp * ICP;
  const int bpix = n0 + wv * 16 + fr;
  const int brow = (bpix / WD + 1) * P + (bpix % WD) + 1;
  f32x4 acc[SPW][4];
#pragma unroll
  for (int p = 0; p < SPW; ++p)
#pragma unroll
    for (int j = 0; j < 4; ++j) acc[p][j] = (f32x4){0, 0, 0, 0};
  auto ISSUE = [&](int buf, int sp) {
#pragma unroll
    for (int h = 0; h < 2; ++h) {
      const int s = sp * 2 + h;
      if (s >= NS) break;
      const int tap = s / KS, k0 = (s - tap * KS) * 32 + kq * 8;
      const int dy = tap / 3 - 1, dx = tap % 3 - 1;
      gl16(&Xb[(size_t)(brow + dy * P + dx) * ICP + k0], &Bl[buf][h][wv][0][0]);
      const u16* wt = Wr + (size_t)tap * 256 * ICP + k0;
#pragma unroll
      for (int p = 0; p < SPW; ++p)
        gl16(&wt[(size_t)(m0 + (wv * SPW + p) * 16 + fr) * ICP],
             &Al[buf][h][wv * SPW + p][0][0]);
    }
  };
  ISSUE(0, 0);
  __syncthreads();
  for (int sp = 0; sp < NPAIR; ++sp) {
    const int cur = sp & 1;
    if (sp + 1 < NPAIR) ISSUE(cur ^ 1, sp + 1);
#pragma unroll
    for (int h = 0; h < 2; ++h) {
      if (sp * 2 + h >= NS) break;
      s16x8 bf[4];
#pragma unroll
      for (int j = 0; j < 4; ++j) bf[j] = *(const s16x8*)&Bl[cur][h][j][lane][0];
#pragma unroll
      for (int p = 0; p < SPW; ++p) {
        s16x8 af = *(const s16x8*)&Al[cur][h][wv * SPW + p][lane][0];
#pragma unroll
        for (int j = 0; j < 4; ++j)
          acc[p][j] = __builtin_amdgcn_mfma_f32_16x16x32_bf16(af, bf[j], acc[p][j], 0, 0, 0);
      }
    }
    __syncthreads();
  }
  const int col = lane & 15, rg = (lane >> 4) * 4;
#pragma unroll
  for (int j = 0; j < 4; ++j) {
    const int nn = n0 + j * 16 + col;
    const size_t rowb = ((size_t)b * HW + nn) * 256;
#pragma unroll
    for (int p = 0; p < SPW; ++p) {
      const int oc0 = m0 + (wv * SPW + p) * 16 + rg;
      u16x4 v;
#pragma unroll
      for (int r = 0; r < 4; ++r)
        v[r] = f2bf(fmaxf(acc[p][j][r] + bias[oc0 + r], 0.0f));
      *(u16x4*)&Y[rowb + oc0] = v;
    }
  }
}

// ---------------------------------------------------------------------------
// Deconv as GEMM (final, fp32 out), DIRECT loads.
// ---------------------------------------------------------------------------
template<int S, int WIN, int MT, bool F32OUT>
__global__ __launch_bounds__(256) void deconv_dir(const u16* __restrict__ X,
    const u16* __restrict__ Wr, const float* __restrict__ bias,
    void* __restrict__ Yout, int Cp, int coff)
{
  constexpr int NP1 = WIN + 1;
  constexpr int Np = NP1 * NP1;
  constexpr int WO = S * WIN;
  constexpr int HWin = WIN * WIN;
  constexpr int Pout = WO + 2, HWpo = Pout * Pout;
  const int tid = threadIdx.x;
  const int lane = tid & 63, wv = tid >> 6;
  const int fr = lane & 15, kq = lane >> 4;
  const int n0 = blockIdx.x * 64, b = blockIdx.y;
  const u16* Xb = X + (size_t)b * HWin * 256 + kq * 8;
  const int pixn = n0 + wv * 16 + fr;
  const int t_y = pixn / NP1, t_x = pixn % NP1;
  f32x4 acc[MT];
#pragma unroll
  for (int mt = 0; mt < MT; ++mt) acc[mt] = (f32x4){0, 0, 0, 0};
#pragma unroll
  for (int tap = 0; tap < 4; ++tap) {
    const int dy = tap >> 1, dx = tap & 1;
    const int iy = t_y - dy, ix = t_x - dx;
    const bool vsp = (pixn < Np) && ((unsigned)iy < (unsigned)WIN) && ((unsigned)ix < (unsigned)WIN);
    const u16* bpt = Xb + (size_t)(vsp ? iy * WIN + ix : 0) * 256;
    for (int kk = 0; kk < 256; kk += 32) {
      s16x8 bf = *(const s16x8*)(bpt + kk);
      if (!vsp) {
#pragma unroll
        for (int i = 0; i < 8; ++i) bf[i] = 0;
      }
#pragma unroll
      for (int mt = 0; mt < MT; ++mt) {
        s16x8 af = *(const s16x8*)&Wr[(size_t)(mt * 16 + fr) * 1024 + tap * 256 + kk + kq * 8];
        acc[mt] = __builtin_amdgcn_mfma_f32_16x16x32_bf16(af, bf, acc[mt], 0, 0, 0);
      }
    }
  }
  const int col = lane & 15, rg = (lane >> 4) * 4;
  const int nn = n0 + wv * 16 + col;
  if (nn >= Np) return;
  const int oty = nn / NP1, otx = nn % NP1;
#pragma unroll
  for (int mt = 0; mt < MT; ++mt) {
#pragma unroll
    for (int r = 0; r < 4; ++r) {
      int m = mt * 16 + rg + r;
      int ph = m >> 1, oc = m & 1;
      if (ph >= S * S) continue;
      int ry = ph / S, rx = ph % S;
      int oy = S * oty + ry - 1, ox = S * otx + rx - 1;
      if ((unsigned)oy >= (unsigned)WO || (unsigned)ox >= (unsigned)WO) continue;
      float v = acc[mt][r] + bias[oc];
      if (F32OUT)
        ((float*)Yout)[((size_t)b * 2 + oc) * WO * WO + (size_t)oy * WO + ox] = v;
      else
        ((u16*)Yout)[((size_t)b * HWpo + (oy + 1) * Pout + ox + 1) * Cp + coff + oc] = f2bf(v);
    }
  }
}

// ---------------------------------------------------------------------------
extern "C" void kernel_launch(void* const* d_in, const int* in_sizes, int n_in,
                              void* d_out, int out_size, void* d_ws, size_t ws_size,
                              hipStream_t stream)
{
  const float* feats_s16 = (const float*)d_in[0];
  const float* feats_s8  = (const float*)d_in[1];
  const float* feats_s4  = (const float*)d_in[2];
  const float* key       = (const float*)d_in[3];
  const float* init_key  = (const float*)d_in[4];
  const float* prev_key  = (const float*)d_in[5];
  const float* init_seg  = (const float*)d_in[6];
  const float* prev_seg  = (const float*)d_in[7];
  const float* mask_f    = (const float*)d_in[8];
  const float* w_conv1 = (const float*)d_in[9];  const float* b_conv1 = (const float*)d_in[10];
  const float* w_blend1= (const float*)d_in[11]; const float* b_blend1= (const float*)d_in[12];
  const float* w_dec1  = (const float*)d_in[13]; const float* b_dec1  = (const float*)d_in[14];
  const float* w_conv2 = (const float*)d_in[15]; const float* b_conv2 = (const float*)d_in[16];
  const float* w_blend2= (const float*)d_in[17]; const float* b_blend2= (const float*)d_in[18];
  const float* w_dec2  = (const float*)d_in[19]; const float* b_dec2  = (const float*)d_in[20];
  const float* w_conv3 = (const float*)d_in[21]; const float* b_conv3 = (const float*)d_in[22];
  const float* w_blend3= (const float*)d_in[23]; const float* b_blend3= (const float*)d_in[24];
  const float* w_dec3  = (const float*)d_in[25]; const float* b_dec3  = (const float*)d_in[26];

  char* ws = (char*)d_ws;
  size_t o = 0;
  auto take = [&](size_t n) { size_t r = o; o += (n + 255) & ~(size_t)255; return r; };
  u16* simG = (u16*)(ws + take((size_t)2 * 2304 * 2304 * 2));
  u16* simL = (u16*)(ws + take((size_t)2 * 2304 * 2304 * 2));
  float* cutv = (float*)(ws + take((size_t)2 * 2304 * 4));
  float* mnv  = (float*)(ws + take((size_t)2 * 2304 * 4));
  float* msc  = (float*)(ws + take((size_t)2 * 4 * 2304 * 4));
  u16* x1  = (u16*)(ws + take((size_t)2 * 2500 * 544 * 2));
  u16* b1o = (u16*)(ws + take((size_t)2 * 2304 * 256 * 2));
  u16* x2  = (u16*)(ws + take((size_t)2 * 9604 * 288 * 2));
  u16* b2o = (u16*)(ws + take((size_t)2 * 9216 * 256 * 2));
  u16* x3  = (u16*)(ws + take((size_t)2 * 37636 * 288 * 2));
  u16* b3o = (u16*)(ws + take((size_t)2 * 36864 * 256 * 2));
  u16* wr1 = (u16*)(ws + take((size_t)9 * 256 * 544 * 2));
  u16* wr2 = (u16*)(ws + take((size_t)9 * 256 * 288 * 2));
  u16* wr3 = (u16*)(ws + take((size_t)9 * 256 * 288 * 2));
  u16* wd1r = (u16*)(ws + take((size_t)16 * 1024 * 2));
  u16* wd2r = (u16*)(ws + take((size_t)16 * 1024 * 2));
  u16* wd3r = (u16*)(ws + take((size_t)32 * 1024 * 2));
  u16* keyT = (u16*)(ws + take((size_t)2 * 2304 * 512 * 2));
  u16* ikT  = (u16*)(ws + take((size_t)2 * 2304 * 512 * 2));
  u16* pkT  = (u16*)(ws + take((size_t)2 * 2304 * 512 * 2));
  u16* wc1b = (u16*)(ws + take((size_t)256 * 1024 * 2));
  u16* wc2b = (u16*)(ws + take((size_t)256 * 512 * 2));
  u16* wc3b = (u16*)(ws + take((size_t)256 * 256 * 2));
  if (o > ws_size) {
    fprintf(stderr, "kernel_launch: ws too small: need %zu, have %zu\n", o, ws_size);
    return;
  }

  // consolidated prologue (2 launches)
  prologue_zero<<<dim3(4096), 256, 0, stream>>>(x1, x2, x3, (u16*)msc);
  prologue_repack<<<dim3(2048), 256, 0, stream>>>(
      w_blend1, w_blend2, w_blend3, w_dec1, w_dec2, w_dec3,
      w_conv1, w_conv2, w_conv3,
      wr1, wr2, wr3, wd1r, wd2r, wd3r, wc1b, wc2b, wc3b);
  trans_key3<<<dim3(36, 8, 6), 256, 0, stream>>>(key, init_key, prev_key, keyT, ikT, pkT);

  // both similarity matrices in one launch (bf16 out, BK=64 pairs, XCD swz)
  sim_gemm_pair2<<<dim3(18, 18, 4), 256, 0, stream>>>(ikT, pkT, keyT, simG, simL);

  // matching scores (rowstats, then both score passes in one launch)
  rowstats<<<dim3(2 * 2304), 256, 0, stream>>>(simL, cutv, mnv);
  score_both<<<dim3(9, 18, 4), 256, 0, stream>>>(simG, simL, init_seg, prev_seg,
      cutv, mnv, msc);

  // stage 1
  conv1x1_bk64<64><<<dim3(36, 4, 2), 256, 0, stream>>>(feats_s16, wc1b, b_conv1, x1, 1024, 48, 544);
  fillmask<<<dim3(2048), 256, 0, stream>>>(msc, mask_f, x1);
  blend3x3_bk64<48, 64, 544><<<dim3(36, 4, 2), 256, 0, stream>>>(x1, wr1, b_blend1, b1o);

  // stage 2: conv2 + deconv1 merged (deconv1 reads b1o, writes x2 ch256..257)
  conv1x1_dec<128, 48><<<dim3(144 + 38, 2, 2), 256, 0, stream>>>(
      feats_s8, wc2b, b_conv2, x2, 512, 96, 288,
      b1o, wd1r, b_dec1, x2, 144);
  blend3x3_bk64<96, 128, 288><<<dim3(144, 2, 2), 256, 0, stream>>>(x2, wr2, b_blend2, b2o);

  // stage 3: conv3 + deconv2 merged (deconv2 reads b2o, writes x3 ch256..257)
  conv1x1_dec<128, 96><<<dim3(576 + 148, 2, 2), 256, 0, stream>>>(
      feats_s4, wc3b, b_conv3, x3, 256, 192, 288,
      b2o, wd2r, b_dec2, x3, 576);
  blend3x3_bk64<192, 128, 288><<<dim3(576, 2, 2), 256, 0, stream>>>(x3, wr3, b_blend3, b3o);
  deconv_dir<4, 192, 2, true><<<dim3((193 * 193 + 63) / 64, 2), 256, 0, stream>>>(
      b3o, wd3r, b_dec3, d_out, 2, 0);
}

// Round 27
// 599.756 us; speedup vs baseline: 1.1050x; 1.1050x over previous
//
#include <hip/hip_runtime.h>
#include <cstdio>

typedef unsigned short u16;
typedef __attribute__((ext_vector_type(4))) float f32x4;
typedef __attribute__((ext_vector_type(8))) short s16x8;
typedef __attribute__((ext_vector_type(4))) unsigned short u16x4;

#define DEV static __device__ __forceinline__

DEV float bf2f(u16 u) { union { unsigned int i; float f; } v; v.i = ((unsigned int)u) << 16; return v.f; }
DEV u16 f2bf(float f) {
  unsigned int x = __float_as_uint(f);
  unsigned int r = (x + 0x7fffu + ((x >> 16) & 1u)) >> 16;
  return (u16)r;
}

typedef const __attribute__((address_space(1))) unsigned int* gptr_t;
typedef __attribute__((address_space(3))) unsigned int* lptr_t;
DEV void gl16(const u16* g, u16* l) {
  __builtin_amdgcn_global_load_lds((gptr_t)g, (lptr_t)l, 16, 0, 0);
}

// XCD-aware chunked block swizzle (requires total blocks % 8 == 0).
DEV void xcd_swz(int& x, int& y, int& z) {
  const int gx = gridDim.x, gy = gridDim.y;
  const int gid = (int)blockIdx.x + gx * ((int)blockIdx.y + gy * (int)blockIdx.z);
  const int cpx = (gx * gy * (int)gridDim.z) >> 3;
  const int sw = (gid & 7) * cpx + (gid >> 3);
  x = sw % gx;
  const int rem = sw / gx;
  y = rem % gy;
  z = rem / gy;
}

// ---------------------------------------------------------------------------
// Prologue zero: all zero-init jobs in one grid-stride kernel.
// ---------------------------------------------------------------------------
DEV void border_pix(int e, int P, int& py, int& px) {
  if (e < P) { py = 0; px = e; }
  else if (e < 2 * P) { py = P - 1; px = e - P; }
  else { int j = e - 2 * P; py = 1 + (j >> 1); px = (j & 1) ? P - 1 : 0; }
}

__global__ __launch_bounds__(256) void prologue_zero(u16* __restrict__ x1,
    u16* __restrict__ x2, u16* __restrict__ x3, u16* __restrict__ mscu)
{
  const long Z1 = 2720000;           // x1 full
  const long Z2 = Z1 + 576240;       // x2 chpad (P=98, 30 ch)
  const long Z3 = Z2 + 223488;       // x2 border (NB=388, 288 ch)
  const long Z4 = Z3 + 2258160;      // x3 chpad (P=194, 30 ch)
  const long Z5 = Z4 + 444672;       // x3 border (NB=772, 288 ch)
  const long Z6 = Z5 + 36864;        // msc as u16
  long i = (long)blockIdx.x * 256 + threadIdx.x;
  const long stride = (long)gridDim.x * 256;
  for (; i < Z6; i += stride) {
    if (i < Z1) {
      x1[i] = 0;
    } else if (i < Z2) {
      long j = i - Z1;
      long pix = j / 30; int c = (int)(j - pix * 30);
      x2[pix * 288 + 258 + c] = 0;
    } else if (i < Z3) {
      long j = i - Z2;
      const int NB = 388;
      long bp = j / 288; int c = (int)(j - bp * 288);
      int b = (int)(bp / NB), e = (int)(bp - (long)b * NB);
      int py, px; border_pix(e, 98, py, px);
      x2[((size_t)b * 9604 + (size_t)py * 98 + px) * 288 + c] = 0;
    } else if (i < Z4) {
      long j = i - Z3;
      long pix = j / 30; int c = (int)(j - pix * 30);
      x3[pix * 288 + 258 + c] = 0;
    } else if (i < Z5) {
      long j = i - Z4;
      const int NB = 772;
      long bp = j / 288; int c = (int)(j - bp * 288);
      int b = (int)(bp / NB), e = (int)(bp - (long)b * NB);
      int py, px; border_pix(e, 194, py, px);
      x3[((size_t)b * 37636 + (size_t)py * 194 + px) * 288 + c] = 0;
    } else {
      mscu[i - Z5] = 0;
    }
  }
}

// ---------------------------------------------------------------------------
// Prologue repack: all weight conversions in one grid-stride kernel.
// ---------------------------------------------------------------------------
DEV u16 dec_repack_elem(const float* w, int j, int S, int KSZ) {
  int m = j >> 10, k = j & 1023;
  int oc = m & 1, ph = m >> 1;
  int tap = k >> 8, ic = k & 255;
  int dy = tap >> 1, dx = tap & 1;
  float val = 0.0f;
  if (ph < S * S) {
    int ry = ph / S, rx = ph % S;
    int ky = ry + S * dy, kx = rx + S * dx;
    if (ky < KSZ && kx < KSZ)
      val = w[((size_t)(ic * 2 + oc) * KSZ + ky) * KSZ + kx];
  }
  return f2bf(val);
}

DEV u16 blend_repack_elem(const float* w, long j, int IC, int ICp) {
  int ic = (int)(j % ICp);
  int oc = (int)((j / ICp) % 256);
  int tap = (int)(j / ((long)ICp * 256));
  return (ic < IC) ? f2bf(w[((size_t)oc * IC + ic) * 9 + tap]) : (u16)0;
}

__global__ __launch_bounds__(256) void prologue_repack(
    const float* __restrict__ wb1, const float* __restrict__ wb2,
    const float* __restrict__ wb3, const float* __restrict__ wd1,
    const float* __restrict__ wd2, const float* __restrict__ wd3,
    const float* __restrict__ wc1, const float* __restrict__ wc2,
    const float* __restrict__ wc3,
    u16* __restrict__ wr1, u16* __restrict__ wr2, u16* __restrict__ wr3,
    u16* __restrict__ wd1r, u16* __restrict__ wd2r, u16* __restrict__ wd3r,
    u16* __restrict__ wc1b, u16* __restrict__ wc2b, u16* __restrict__ wc3b)
{
  const long N1 = 1253376;          // wr1 (544)
  const long N2 = N1 + 663552;      // wr2 (288)
  const long N3 = N2 + 663552;      // wr3 (288)
  const long N4 = N3 + 16384;       // wd1r
  const long N5 = N4 + 16384;       // wd2r
  const long N6 = N5 + 32768;       // wd3r
  const long N7 = N6 + 262144;      // wc1b
  const long N8 = N7 + 131072;      // wc2b
  const long N9 = N8 + 65536;       // wc3b
  long i = (long)blockIdx.x * 256 + threadIdx.x;
  const long stride = (long)gridDim.x * 256;
  for (; i < N9; i += stride) {
    if (i < N1) {
      wr1[i] = blend_repack_elem(wb1, i, 516, 544);
    } else if (i < N2) {
      long j = i - N1; wr2[j] = blend_repack_elem(wb2, j, 258, 288);
    } else if (i < N3) {
      long j = i - N2; wr3[j] = blend_repack_elem(wb3, j, 258, 288);
    } else if (i < N4) {
      int j = (int)(i - N3); wd1r[j] = dec_repack_elem(wd1, j, 2, 4);
    } else if (i < N5) {
      int j = (int)(i - N4); wd2r[j] = dec_repack_elem(wd2, j, 2, 4);
    } else if (i < N6) {
      int j = (int)(i - N5); wd3r[j] = dec_repack_elem(wd3, j, 4, 6);
    } else if (i < N7) {
      long j = i - N6; wc1b[j] = f2bf(wc1[j]);
    } else if (i < N8) {
      long j = i - N7; wc2b[j] = f2bf(wc2[j]);
    } else {
      long j = i - N8; wc3b[j] = f2bf(wc3[j]);
    }
  }
}

// ---------------------------------------------------------------------------
// key transpose x3: fp32 [B][512][2304] -> bf16 [B][2304][512].
// ---------------------------------------------------------------------------
__global__ __launch_bounds__(256) void trans_key3(const float* __restrict__ k0,
    const float* __restrict__ k1, const float* __restrict__ k2,
    u16* __restrict__ y0, u16* __restrict__ y1, u16* __restrict__ y2)
{
  __shared__ u16 t[64][72];
  const int tid = threadIdx.x;
  const int z = blockIdx.z;
  const float* X = (z < 2) ? k0 : (z < 4) ? k1 : k2;
  u16* Y = (z < 2) ? y0 : (z < 4) ? y1 : y2;
  const int b = z & 1;
  const int n0 = blockIdx.x * 64, k0i = blockIdx.y * 64;
  const float* Xb = X + (size_t)b * 512 * 2304;
  const int nl = tid & 63, kr = tid >> 6;
#pragma unroll
  for (int kk = 0; kk < 16; ++kk) {
    int kl = kr + kk * 4;
    t[kl][nl] = f2bf(Xb[(size_t)(k0i + kl) * 2304 + n0 + nl]);
  }
  __syncthreads();
  const int nr = tid >> 2, kb = (tid & 3) * 16;
  u16* yp = Y + (size_t)b * 2304 * 512 + (size_t)(n0 + nr) * 512 + k0i + kb;
#pragma unroll
  for (int i = 0; i < 4; ++i) {
    u16x4 v;
#pragma unroll
    for (int e = 0; e < 4; ++e) v[e] = t[kb + i * 4 + e][nr];
    *(u16x4*)&yp[i * 4] = v;
  }
}

// ---------------------------------------------------------------------------
// Both similarity GEMMs in one launch. 128x128 tile, BK=64 pairs, gload_lds.
// grid (18,18,4) = 1296 blocks (%8==0) -> XCD swizzle applied.
// ---------------------------------------------------------------------------
__global__ __launch_bounds__(256) void sim_gemm_pair2(const u16* __restrict__ ikT,
    const u16* __restrict__ pkT, const u16* __restrict__ keyT,
    u16* __restrict__ simG, u16* __restrict__ simL)
{
  __shared__ alignas(16) u16 Al[2][2][8][64][8];
  __shared__ alignas(16) u16 Bl[2][2][8][64][8];
  const int tid = threadIdx.x;
  const int lane = tid & 63, wv = tid >> 6;
  const int fr = lane & 15, kq = lane >> 4;
  const int wr = wv >> 1, wc = wv & 1;
  int bx, by, z;
  xcd_swz(bx, by, z);
  const u16* AT = (z < 2) ? ikT : pkT;
  u16* out = (z < 2) ? simG : simL;
  const int b = z & 1;
  const int n0 = bx * 128, m0 = by * 128;
  const u16* Ab = AT + (size_t)b * 2304 * 512;
  const u16* Bb = keyT + (size_t)b * 2304 * 512;
  const int ar0 = m0 + wv * 16 + fr, ar1 = m0 + (wv + 4) * 16 + fr;
  const int br0 = n0 + wv * 16 + fr, br1 = n0 + (wv + 4) * 16 + fr;
  f32x4 acc[4][4];
#pragma unroll
  for (int p = 0; p < 4; ++p)
#pragma unroll
    for (int j = 0; j < 4; ++j) acc[p][j] = (f32x4){0, 0, 0, 0};
  auto ISSUE = [&](int buf, int sp) {
#pragma unroll
    for (int h = 0; h < 2; ++h) {
      const int k0 = (sp * 2 + h) * 32 + kq * 8;
      gl16(&Ab[(size_t)ar0 * 512 + k0], &Al[buf][h][wv][0][0]);
      gl16(&Ab[(size_t)ar1 * 512 + k0], &Al[buf][h][wv + 4][0][0]);
      gl16(&Bb[(size_t)br0 * 512 + k0], &Bl[buf][h][wv][0][0]);
      gl16(&Bb[(size_t)br1 * 512 + k0], &Bl[buf][h][wv + 4][0][0]);
    }
  };
  ISSUE(0, 0);
  __syncthreads();
  const int NPAIR = 512 / 64;
  for (int sp = 0; sp < NPAIR; ++sp) {
    const int cur = sp & 1;
    if (sp + 1 < NPAIR) ISSUE(cur ^ 1, sp + 1);
#pragma unroll
    for (int h = 0; h < 2; ++h) {
      s16x8 bf[4], af[4];
#pragma unroll
      for (int j = 0; j < 4; ++j) bf[j] = *(const s16x8*)&Bl[cur][h][wc * 4 + j][lane][0];
#pragma unroll
      for (int p = 0; p < 4; ++p) af[p] = *(const s16x8*)&Al[cur][h][wr * 4 + p][lane][0];
#pragma unroll
      for (int p = 0; p < 4; ++p)
#pragma unroll
        for (int j = 0; j < 4; ++j)
          acc[p][j] = __builtin_amdgcn_mfma_f32_16x16x32_bf16(af[p], bf[j], acc[p][j], 0, 0, 0);
    }
    __syncthreads();
  }
  const int col = lane & 15, rg = (lane >> 4) * 4;
#pragma unroll
  for (int p = 0; p < 4; ++p)
#pragma unroll
    for (int j = 0; j < 4; ++j)
#pragma unroll
      for (int r = 0; r < 4; ++r) {
        int pr = m0 + (wr * 4 + p) * 16 + rg + r;
        int q = n0 + (wc * 4 + j) * 16 + col;
        out[((size_t)b * 2304 + pr) * 2304 + q] = f2bf((acc[p][j][r] + 1.0f) * 0.5f);
      }
}

// ---------------------------------------------------------------------------
// Per-row stats of local_sim (bf16): cut = 4th-largest over q, mn = min.
// ---------------------------------------------------------------------------
__global__ __launch_bounds__(256) void rowstats(const u16* __restrict__ simL,
    float* __restrict__ cutv, float* __restrict__ mnv)
{
  const int row = blockIdx.x;
  const int tid = threadIdx.x;
  const u16* r = simL + (size_t)row * 2304;
  float t0 = -1e30f, t1 = -1e30f, t2 = -1e30f, t3 = -1e30f, mn = 1e30f;
  for (int i = tid; i < 2304; i += 256) {
    float v = bf2f(r[i]);
    mn = fminf(mn, v);
    if (v > t3) {
      if (v > t2) { t3 = t2; if (v > t1) { t2 = t1; if (v > t0) { t1 = t0; t0 = v; } else t1 = v; } else t2 = v; }
      else t3 = v;
    }
  }
  __shared__ float s4[256][4];
  __shared__ float smv[256];
  s4[tid][0] = t0; s4[tid][1] = t1; s4[tid][2] = t2; s4[tid][3] = t3;
  smv[tid] = mn;
  __syncthreads();
  for (int s = 128; s > 0; s >>= 1) {
    if (tid < s) {
      float a0 = s4[tid][0], a1 = s4[tid][1], a2 = s4[tid][2], a3 = s4[tid][3];
      float b0 = s4[tid + s][0], b1 = s4[tid + s][1], b2 = s4[tid + s][2], b3 = s4[tid + s][3];
      float m0 = fmaxf(a0, b3), m1 = fmaxf(a1, b2), m2 = fmaxf(a2, b1), m3 = fmaxf(a3, b0);
      float c0 = fmaxf(m0, m2), c2 = fminf(m0, m2), c1 = fmaxf(m1, m3), c3 = fminf(m1, m3);
      s4[tid][0] = fmaxf(c0, c1); s4[tid][1] = fminf(c0, c1);
      s4[tid][2] = fmaxf(c2, c3); s4[tid][3] = fminf(c2, c3);
      smv[tid] = fminf(smv[tid], smv[tid + s]);
    }
    __syncthreads();
  }
  if (tid == 0) { cutv[row] = s4[0][3]; mnv[row] = smv[0]; }
}

// ---------------------------------------------------------------------------
// Both score passes in one launch. grid (9,18,4).
// ---------------------------------------------------------------------------
__global__ __launch_bounds__(256) void score_both(const u16* __restrict__ simG,
    const u16* __restrict__ simL, const float* __restrict__ init_seg,
    const float* __restrict__ prev_seg, const float* __restrict__ cutv,
    const float* __restrict__ mnv, float* __restrict__ msc)
{
  const int z = blockIdx.z;
  const bool loc = (z >= 2);
  const int b = z & 1;
  const u16* sim = loc ? simL : simG;
  const float* seg = loc ? prev_seg : init_seg;
  const int chBase = loc ? 2 : 0;
  const int q = blockIdx.x * 256 + threadIdx.x;
  const int p0 = blockIdx.y * 128;
  const u16* sp = sim + ((size_t)b * 2304 + p0) * 2304 + q;
  const float* sg = seg + (size_t)b * 2 * 2304;
  const float* cu = cutv + (size_t)b * 2304 + p0;
  const float* ml = mnv + (size_t)b * 2304 + p0;
  float m0 = 0.0f, m1 = 0.0f;
  if (loc) {
    for (int p = 0; p < 128; ++p) {
      float sv = bf2f(sp[(size_t)p * 2304]);
      float cut = cu[p], mnr = ml[p];
      float mv = (sv < cut) ? mnr : sv;
      float s0 = sg[p0 + p];
      float s1 = sg[2304 + p0 + p];
      m0 = fmaxf(m0, mv * s0);
      m1 = fmaxf(m1, mv * s1);
    }
  } else {
    for (int p = 0; p < 128; ++p) {
      float sv = bf2f(sp[(size_t)p * 2304]);
      float s0 = sg[p0 + p];
      float s1 = sg[2304 + p0 + p];
      m0 = fmaxf(m0, sv * s0);
      m1 = fmaxf(m1, sv * s1);
    }
  }
  atomicMax((int*)&msc[((size_t)b * 4 + chBase) * 2304 + q], __float_as_int(m0));
  atomicMax((int*)&msc[((size_t)b * 4 + chBase + 1) * 2304 + q], __float_as_int(m1));
}

// ---------------------------------------------------------------------------
// fill_scores + copy_mask merged: flat grid-stride.
// ---------------------------------------------------------------------------
__global__ __launch_bounds__(256) void fillmask(const float* __restrict__ msc,
    const float* __restrict__ mask, u16* __restrict__ x1)
{
  const long NSC = 2 * 2304;
  const long NMK = NSC + (long)2 * 256 * 2304;
  long i = (long)blockIdx.x * 256 + threadIdx.x;
  const long stride = (long)gridDim.x * 256;
  for (; i < NMK; i += stride) {
    if (i < NSC) {
      int idx = (int)i;
      int b = idx / 2304, q = idx % 2304;
      int py = q / 48, px = q % 48;
      u16x4 v;
#pragma unroll
      for (int c = 0; c < 4; ++c) v[c] = f2bf(msc[((size_t)b * 4 + c) * 2304 + q]);
      *(u16x4*)&x1[((size_t)b * 2500 + (py + 1) * 50 + px + 1) * 544 + 256] = v;
    } else {
      long j = i - NSC;
      int b = (int)(j / (256 * 2304));
      int r = (int)(j - (long)b * 256 * 2304);
      int c = r / 2304, q = r % 2304;
      int py = q / 48, px = q % 48;
      x1[((size_t)b * 2500 + (py + 1) * 50 + px + 1) * 544 + 260 + c] = f2bf(mask[j]);
    }
  }
}

// ---------------------------------------------------------------------------
// 1x1 conv: A (bf16 weights) via gload_lds, B (fp32 NCHW X) reg-converted.
// BK=64 pairs. grid (NBLK, MBLK, B). Y: NHWC padded bf16, ch 0..255.
// ---------------------------------------------------------------------------
template<int MB>
__global__ __launch_bounds__(256) void conv1x1_bk64(const float* __restrict__ X,
    const u16* __restrict__ Wb, const float* __restrict__ bias,
    u16* __restrict__ Y, int K, int WD, int Cp)
{
  const int N = WD * WD;
  const int P = WD + 2, HWp = P * P;
  constexpr int SUB = MB / 16, SPW = SUB / 4;
  __shared__ alignas(16) u16 Al[2][2][SUB][64][8];
  __shared__ alignas(16) u16 Bl[2][2][4][64][8];
  const int tid = threadIdx.x;
  const int n0 = blockIdx.x * 64, m0 = blockIdx.y * MB, b = blockIdx.z;
  const int lane = tid & 63, wv = tid >> 6;
  const int fr = lane & 15, kq = lane >> 4;
  const float* Xb = X + (size_t)b * K * N;
  const int bpix = n0 + wv * 16 + fr;
  f32x4 acc[SPW][4];
#pragma unroll
  for (int p = 0; p < SPW; ++p)
#pragma unroll
    for (int j = 0; j < 4; ++j) acc[p][j] = (f32x4){0, 0, 0, 0};
  s16x8 bN[2];
  auto ISSUEA = [&](int buf, int sp) {
#pragma unroll
    for (int h = 0; h < 2; ++h) {
      const int k0 = (sp * 2 + h) * 32 + kq * 8;
#pragma unroll
      for (int p = 0; p < SPW; ++p)
        gl16(&Wb[(size_t)(m0 + (wv * SPW + p) * 16 + fr) * K + k0],
             &Al[buf][h][wv * SPW + p][0][0]);
    }
  };
  auto LDB = [&](int sp) {
#pragma unroll
    for (int h = 0; h < 2; ++h) {
      const int k0 = (sp * 2 + h) * 32;
#pragma unroll
      for (int i = 0; i < 8; ++i)
        bN[h][i] = (short)f2bf(Xb[(size_t)(k0 + kq * 8 + i) * N + bpix]);
    }
  };
  auto STB = [&](int buf) {
#pragma unroll
    for (int h = 0; h < 2; ++h) *(s16x8*)&Bl[buf][h][wv][lane][0] = bN[h];
  };
  ISSUEA(0, 0); LDB(0); STB(0);
  __syncthreads();
  const int NPAIR = K / 64;
  for (int sp = 0; sp < NPAIR; ++sp) {
    const int cur = sp & 1;
    const bool more = (sp + 1) < NPAIR;
    if (more) { ISSUEA(cur ^ 1, sp + 1); LDB(sp + 1); }
#pragma unroll
    for (int h = 0; h < 2; ++h) {
      s16x8 bf[4];
#pragma unroll
      for (int j = 0; j < 4; ++j) bf[j] = *(const s16x8*)&Bl[cur][h][j][lane][0];
#pragma unroll
      for (int p = 0; p < SPW; ++p) {
        s16x8 af = *(const s16x8*)&Al[cur][h][wv * SPW + p][lane][0];
#pragma unroll
        for (int j = 0; j < 4; ++j)
          acc[p][j] = __builtin_amdgcn_mfma_f32_16x16x32_bf16(af, bf[j], acc[p][j], 0, 0, 0);
      }
    }
    if (more) STB(cur ^ 1);
    __syncthreads();
  }
  const int col = lane & 15, rg = (lane >> 4) * 4;
#pragma unroll
  for (int j = 0; j < 4; ++j) {
    const int nn = n0 + j * 16 + col;
    const int py = nn / WD, px = nn % WD;
    const size_t rowb = ((size_t)b * HWp + (py + 1) * P + px + 1) * Cp;
#pragma unroll
    for (int p = 0; p < SPW; ++p) {
      const int oc0 = m0 + (wv * SPW + p) * 16 + rg;
      u16x4 v;
#pragma unroll
      for (int r = 0; r < 4; ++r)
        v[r] = f2bf(fmaxf(acc[p][j][r] + bias[oc0 + r], 0.0f));
      *(u16x4*)&Y[rowb + oc0] = v;
    }
  }
}

// ---------------------------------------------------------------------------
// MERGED: conv1x1 (as above) + deconv s=2 (bf16 out) in one launch.
// blockIdx.x < NCONVX -> conv path; else (y==0 only) -> deconv path with
// pixel block n0d = (x - NCONVX)*64, b = blockIdx.z. Outputs disjoint chans.
// ---------------------------------------------------------------------------
template<int MB, int DWIN>
__global__ __launch_bounds__(256) void conv1x1_dec(const float* __restrict__ X,
    const u16* __restrict__ Wb, const float* __restrict__ bias,
    u16* __restrict__ Y, int K, int WD, int Cp,
    const u16* __restrict__ DX, const u16* __restrict__ DWr,
    const float* __restrict__ Dbias, u16* __restrict__ DY, int NCONVX)
{
  constexpr int SUB = MB / 16, SPW = SUB / 4;
  __shared__ alignas(16) u16 Al[2][2][SUB][64][8];
  __shared__ alignas(16) u16 Bl[2][2][4][64][8];
  const int tid = threadIdx.x;
  const int lane = tid & 63, wv = tid >> 6;
  const int fr = lane & 15, kq = lane >> 4;
  const int b = blockIdx.z;
  if ((int)blockIdx.x >= NCONVX) {
    // ---- deconv path (S=2, MT=1, bf16 out into DY ch 256..257 of Cp) ----
    if (blockIdx.y != 0) return;
    constexpr int NP1 = DWIN + 1;
    constexpr int Np = NP1 * NP1;
    constexpr int WO = 2 * DWIN;
    constexpr int HWin = DWIN * DWIN;
    constexpr int Pout = WO + 2;
    constexpr int HWpo = Pout * Pout;
    const int n0 = ((int)blockIdx.x - NCONVX) * 64;
    const u16* Xb = DX + (size_t)b * HWin * 256 + kq * 8;
    const int pixn = n0 + wv * 16 + fr;
    const int t_y = pixn / NP1, t_x = pixn % NP1;
    f32x4 acc = {0, 0, 0, 0};
#pragma unroll
    for (int tap = 0; tap < 4; ++tap) {
      const int dy = tap >> 1, dx = tap & 1;
      const int iy = t_y - dy, ix = t_x - dx;
      const bool vsp = (pixn < Np) && ((unsigned)iy < (unsigned)DWIN) && ((unsigned)ix < (unsigned)DWIN);
      const u16* bpt = Xb + (size_t)(vsp ? iy * DWIN + ix : 0) * 256;
      for (int kk = 0; kk < 256; kk += 32) {
        s16x8 bf = *(const s16x8*)(bpt + kk);
        if (!vsp) {
#pragma unroll
          for (int i = 0; i < 8; ++i) bf[i] = 0;
        }
        s16x8 af = *(const s16x8*)&DWr[(size_t)fr * 1024 + tap * 256 + kk + kq * 8];
        acc = __builtin_amdgcn_mfma_f32_16x16x32_bf16(af, bf, acc, 0, 0, 0);
      }
    }
    const int col = lane & 15, rg = (lane >> 4) * 4;
    const int nn = n0 + wv * 16 + col;
    if (nn >= Np) return;
    const int oty = nn / NP1, otx = nn % NP1;
#pragma unroll
    for (int r = 0; r < 4; ++r) {
      int m = rg + r;
      int ph = m >> 1, oc = m & 1;
      if (ph >= 4) continue;
      int ry = ph >> 1, rx = ph & 1;
      int oy = 2 * oty + ry - 1, ox = 2 * otx + rx - 1;
      if ((unsigned)oy >= (unsigned)WO || (unsigned)ox >= (unsigned)WO) continue;
      float v = acc[r] + Dbias[oc];
      DY[((size_t)b * HWpo + (oy + 1) * Pout + ox + 1) * Cp + 256 + oc] = f2bf(v);
    }
    return;
  }
  // ---- conv path (identical to conv1x1_bk64) ----
  const int N = WD * WD;
  const int P = WD + 2, HWp = P * P;
  const int n0 = blockIdx.x * 64, m0 = blockIdx.y * MB;
  const float* Xb = X + (size_t)b * K * N;
  const int bpix = n0 + wv * 16 + fr;
  f32x4 acc[SPW][4];
#pragma unroll
  for (int p = 0; p < SPW; ++p)
#pragma unroll
    for (int j = 0; j < 4; ++j) acc[p][j] = (f32x4){0, 0, 0, 0};
  s16x8 bN[2];
  auto ISSUEA = [&](int buf, int sp) {
#pragma unroll
    for (int h = 0; h < 2; ++h) {
      const int k0 = (sp * 2 + h) * 32 + kq * 8;
#pragma unroll
      for (int p = 0; p < SPW; ++p)
        gl16(&Wb[(size_t)(m0 + (wv * SPW + p) * 16 + fr) * K + k0],
             &Al[buf][h][wv * SPW + p][0][0]);
    }
  };
  auto LDB = [&](int sp) {
#pragma unroll
    for (int h = 0; h < 2; ++h) {
      const int k0 = (sp * 2 + h) * 32;
#pragma unroll
      for (int i = 0; i < 8; ++i)
        bN[h][i] = (short)f2bf(Xb[(size_t)(k0 + kq * 8 + i) * N + bpix]);
    }
  };
  auto STB = [&](int buf) {
#pragma unroll
    for (int h = 0; h < 2; ++h) *(s16x8*)&Bl[buf][h][wv][lane][0] = bN[h];
  };
  ISSUEA(0, 0); LDB(0); STB(0);
  __syncthreads();
  const int NPAIR = K / 64;
  for (int sp = 0; sp < NPAIR; ++sp) {
    const int cur = sp & 1;
    const bool more = (sp + 1) < NPAIR;
    if (more) { ISSUEA(cur ^ 1, sp + 1); LDB(sp + 1); }
#pragma unroll
    for (int h = 0; h < 2; ++h) {
      s16x8 bf[4];
#pragma unroll
      for (int j = 0; j < 4; ++j) bf[j] = *(const s16x8*)&Bl[cur][h][j][lane][0];
#pragma unroll
      for (int p = 0; p < SPW; ++p) {
        s16x8 af = *(const s16x8*)&Al[cur][h][wv * SPW + p][lane][0];
#pragma unroll
        for (int j = 0; j < 4; ++j)
          acc[p][j] = __builtin_amdgcn_mfma_f32_16x16x32_bf16(af, bf[j], acc[p][j], 0, 0, 0);
      }
    }
    if (more) STB(cur ^ 1);
    __syncthreads();
  }
  const int col = lane & 15, rg = (lane >> 4) * 4;
#pragma unroll
  for (int j = 0; j < 4; ++j) {
    const int nn = n0 + j * 16 + col;
    const int py = nn / WD, px = nn % WD;
    const size_t rowb = ((size_t)b * HWp + (py + 1) * P + px + 1) * Cp;
#pragma unroll
    for (int p = 0; p < SPW; ++p) {
      const int oc0 = m0 + (wv * SPW + p) * 16 + rg;
      u16x4 v;
#pragma unroll
      for (int r = 0; r < 4; ++r)
        v[r] = f2bf(fmaxf(acc[p][j][r] + bias[oc0 + r], 0.0f));
      *(u16x4*)&Y[rowb + oc0] = v;
    }
  }
}

// ---------------------------------------------------------------------------
// 3x3 conv pad1 + relu, MB x 64 tile, BK=64 pairs, gload_lds, XCD swizzle.
// Runtime ICp (R26's templatized ICP regressed: codegen perturbation).
// ---------------------------------------------------------------------------
template<int WD, int MB>
__global__ __launch_bounds__(256) void blend3x3_bk64(const u16* __restrict__ X,
    const u16* __restrict__ Wr, const float* __restrict__ bias,
    u16* __restrict__ Y, int ICp)
{
  constexpr int P = WD + 2, HWp = P * P, HW = WD * WD;
  constexpr int SUB = MB / 16, SPW = SUB / 4;
  __shared__ alignas(16) u16 Al[2][2][SUB][64][8];
  __shared__ alignas(16) u16 Bl[2][2][4][64][8];
  const int tid = threadIdx.x;
  const int lane = tid & 63, wv = tid >> 6;
  const int fr = lane & 15, kq = lane >> 4;
  int bx, by, bz;
  xcd_swz(bx, by, bz);
  const int n0 = bx * 64, m0 = by * MB, b = bz;
  const int KS = ICp / 32, NS = 9 * KS;
  const int NPAIR = (NS + 1) / 2;
  const u16* Xb = X + (size_t)b * HWp * ICp;
  const int bpix = n0 + wv * 16 + fr;
  const int brow = (bpix / WD + 1) * P + (bpix % WD) + 1;
  f32x4 acc[SPW][4];
#pragma unroll
  for (int p = 0; p < SPW; ++p)
#pragma unroll
    for (int j = 0; j < 4; ++j) acc[p][j] = (f32x4){0, 0, 0, 0};
  auto ISSUE = [&](int buf, int sp) {
#pragma unroll
    for (int h = 0; h < 2; ++h) {
      const int s = sp * 2 + h;
      if (s >= NS) break;
      const int tap = s / KS, k0 = (s - tap * KS) * 32 + kq * 8;
      const int dy = tap / 3 - 1, dx = tap % 3 - 1;
      gl16(&Xb[(size_t)(brow + dy * P + dx) * ICp + k0], &Bl[buf][h][wv][0][0]);
      const u16* wt = Wr + (size_t)tap * 256 * ICp + k0;
#pragma unroll
      for (int p = 0; p < SPW; ++p)
        gl16(&wt[(size_t)(m0 + (wv * SPW + p) * 16 + fr) * ICp],
             &Al[buf][h][wv * SPW + p][0][0]);
    }
  };
  ISSUE(0, 0);
  __syncthreads();
  for (int sp = 0; sp < NPAIR; ++sp) {
    const int cur = sp & 1;
    if (sp + 1 < NPAIR) ISSUE(cur ^ 1, sp + 1);
#pragma unroll
    for (int h = 0; h < 2; ++h) {
      if (sp * 2 + h >= NS) break;
      s16x8 bf[4];
#pragma unroll
      for (int j = 0; j < 4; ++j) bf[j] = *(const s16x8*)&Bl[cur][h][j][lane][0];
#pragma unroll
      for (int p = 0; p < SPW; ++p) {
        s16x8 af = *(const s16x8*)&Al[cur][h][wv * SPW + p][lane][0];
#pragma unroll
        for (int j = 0; j < 4; ++j)
          acc[p][j] = __builtin_amdgcn_mfma_f32_16x16x32_bf16(af, bf[j], acc[p][j], 0, 0, 0);
      }
    }
    __syncthreads();
  }
  const int col = lane & 15, rg = (lane >> 4) * 4;
#pragma unroll
  for (int j = 0; j < 4; ++j) {
    const int nn = n0 + j * 16 + col;
    const size_t rowb = ((size_t)b * HW + nn) * 256;
#pragma unroll
    for (int p = 0; p < SPW; ++p) {
      const int oc0 = m0 + (wv * SPW + p) * 16 + rg;
      u16x4 v;
#pragma unroll
      for (int r = 0; r < 4; ++r)
        v[r] = f2bf(fmaxf(acc[p][j][r] + bias[oc0 + r], 0.0f));
      *(u16x4*)&Y[rowb + oc0] = v;
    }
  }
}

// ---------------------------------------------------------------------------
// Deconv as GEMM (final, fp32 out), DIRECT loads.
// ---------------------------------------------------------------------------
template<int S, int WIN, int MT, bool F32OUT>
__global__ __launch_bounds__(256) void deconv_dir(const u16* __restrict__ X,
    const u16* __restrict__ Wr, const float* __restrict__ bias,
    void* __restrict__ Yout, int Cp, int coff)
{
  constexpr int NP1 = WIN + 1;
  constexpr int Np = NP1 * NP1;
  constexpr int WO = S * WIN;
  constexpr int HWin = WIN * WIN;
  constexpr int Pout = WO + 2, HWpo = Pout * Pout;
  const int tid = threadIdx.x;
  const int lane = tid & 63, wv = tid >> 6;
  const int fr = lane & 15, kq = lane >> 4;
  const int n0 = blockIdx.x * 64, b = blockIdx.y;
  const u16* Xb = X + (size_t)b * HWin * 256 + kq * 8;
  const int pixn = n0 + wv * 16 + fr;
  const int t_y = pixn / NP1, t_x = pixn % NP1;
  f32x4 acc[MT];
#pragma unroll
  for (int mt = 0; mt < MT; ++mt) acc[mt] = (f32x4){0, 0, 0, 0};
#pragma unroll
  for (int tap = 0; tap < 4; ++tap) {
    const int dy = tap >> 1, dx = tap & 1;
    const int iy = t_y - dy, ix = t_x - dx;
    const bool vsp = (pixn < Np) && ((unsigned)iy < (unsigned)WIN) && ((unsigned)ix < (unsigned)WIN);
    const u16* bpt = Xb + (size_t)(vsp ? iy * WIN + ix : 0) * 256;
    for (int kk = 0; kk < 256; kk += 32) {
      s16x8 bf = *(const s16x8*)(bpt + kk);
      if (!vsp) {
#pragma unroll
        for (int i = 0; i < 8; ++i) bf[i] = 0;
      }
#pragma unroll
      for (int mt = 0; mt < MT; ++mt) {
        s16x8 af = *(const s16x8*)&Wr[(size_t)(mt * 16 + fr) * 1024 + tap * 256 + kk + kq * 8];
        acc[mt] = __builtin_amdgcn_mfma_f32_16x16x32_bf16(af, bf, acc[mt], 0, 0, 0);
      }
    }
  }
  const int col = lane & 15, rg = (lane >> 4) * 4;
  const int nn = n0 + wv * 16 + col;
  if (nn >= Np) return;
  const int oty = nn / NP1, otx = nn % NP1;
#pragma unroll
  for (int mt = 0; mt < MT; ++mt) {
#pragma unroll
    for (int r = 0; r < 4; ++r) {
      int m = mt * 16 + rg + r;
      int ph = m >> 1, oc = m & 1;
      if (ph >= S * S) continue;
      int ry = ph / S, rx = ph % S;
      int oy = S * oty + ry - 1, ox = S * otx + rx - 1;
      if ((unsigned)oy >= (unsigned)WO || (unsigned)ox >= (unsigned)WO) continue;
      float v = acc[mt][r] + bias[oc];
      if (F32OUT)
        ((float*)Yout)[((size_t)b * 2 + oc) * WO * WO + (size_t)oy * WO + ox] = v;
      else
        ((u16*)Yout)[((size_t)b * HWpo + (oy + 1) * Pout + ox + 1) * Cp + coff + oc] = f2bf(v);
    }
  }
}

// ---------------------------------------------------------------------------
extern "C" void kernel_launch(void* const* d_in, const int* in_sizes, int n_in,
                              void* d_out, int out_size, void* d_ws, size_t ws_size,
                              hipStream_t stream)
{
  const float* feats_s16 = (const float*)d_in[0];
  const float* feats_s8  = (const float*)d_in[1];
  const float* feats_s4  = (const float*)d_in[2];
  const float* key       = (const float*)d_in[3];
  const float* init_key  = (const float*)d_in[4];
  const float* prev_key  = (const float*)d_in[5];
  const float* init_seg  = (const float*)d_in[6];
  const float* prev_seg  = (const float*)d_in[7];
  const float* mask_f    = (const float*)d_in[8];
  const float* w_conv1 = (const float*)d_in[9];  const float* b_conv1 = (const float*)d_in[10];
  const float* w_blend1= (const float*)d_in[11]; const float* b_blend1= (const float*)d_in[12];
  const float* w_dec1  = (const float*)d_in[13]; const float* b_dec1  = (const float*)d_in[14];
  const float* w_conv2 = (const float*)d_in[15]; const float* b_conv2 = (const float*)d_in[16];
  const float* w_blend2= (const float*)d_in[17]; const float* b_blend2= (const float*)d_in[18];
  const float* w_dec2  = (const float*)d_in[19]; const float* b_dec2  = (const float*)d_in[20];
  const float* w_conv3 = (const float*)d_in[21]; const float* b_conv3 = (const float*)d_in[22];
  const float* w_blend3= (const float*)d_in[23]; const float* b_blend3= (const float*)d_in[24];
  const float* w_dec3  = (const float*)d_in[25]; const float* b_dec3  = (const float*)d_in[26];

  char* ws = (char*)d_ws;
  size_t o = 0;
  auto take = [&](size_t n) { size_t r = o; o += (n + 255) & ~(size_t)255; return r; };
  u16* simG = (u16*)(ws + take((size_t)2 * 2304 * 2304 * 2));
  u16* simL = (u16*)(ws + take((size_t)2 * 2304 * 2304 * 2));
  float* cutv = (float*)(ws + take((size_t)2 * 2304 * 4));
  float* mnv  = (float*)(ws + take((size_t)2 * 2304 * 4));
  float* msc  = (float*)(ws + take((size_t)2 * 4 * 2304 * 4));
  u16* x1  = (u16*)(ws + take((size_t)2 * 2500 * 544 * 2));
  u16* b1o = (u16*)(ws + take((size_t)2 * 2304 * 256 * 2));
  u16* x2  = (u16*)(ws + take((size_t)2 * 9604 * 288 * 2));
  u16* b2o = (u16*)(ws + take((size_t)2 * 9216 * 256 * 2));
  u16* x3  = (u16*)(ws + take((size_t)2 * 37636 * 288 * 2));
  u16* b3o = (u16*)(ws + take((size_t)2 * 36864 * 256 * 2));
  u16* wr1 = (u16*)(ws + take((size_t)9 * 256 * 544 * 2));
  u16* wr2 = (u16*)(ws + take((size_t)9 * 256 * 288 * 2));
  u16* wr3 = (u16*)(ws + take((size_t)9 * 256 * 288 * 2));
  u16* wd1r = (u16*)(ws + take((size_t)16 * 1024 * 2));
  u16* wd2r = (u16*)(ws + take((size_t)16 * 1024 * 2));
  u16* wd3r = (u16*)(ws + take((size_t)32 * 1024 * 2));
  u16* keyT = (u16*)(ws + take((size_t)2 * 2304 * 512 * 2));
  u16* ikT  = (u16*)(ws + take((size_t)2 * 2304 * 512 * 2));
  u16* pkT  = (u16*)(ws + take((size_t)2 * 2304 * 512 * 2));
  u16* wc1b = (u16*)(ws + take((size_t)256 * 1024 * 2));
  u16* wc2b = (u16*)(ws + take((size_t)256 * 512 * 2));
  u16* wc3b = (u16*)(ws + take((size_t)256 * 256 * 2));
  if (o > ws_size) {
    fprintf(stderr, "kernel_launch: ws too small: need %zu, have %zu\n", o, ws_size);
    return;
  }

  // consolidated prologue (2 launches)
  prologue_zero<<<dim3(4096), 256, 0, stream>>>(x1, x2, x3, (u16*)msc);
  prologue_repack<<<dim3(2048), 256, 0, stream>>>(
      w_blend1, w_blend2, w_blend3, w_dec1, w_dec2, w_dec3,
      w_conv1, w_conv2, w_conv3,
      wr1, wr2, wr3, wd1r, wd2r, wd3r, wc1b, wc2b, wc3b);
  trans_key3<<<dim3(36, 8, 6), 256, 0, stream>>>(key, init_key, prev_key, keyT, ikT, pkT);

  // both similarity matrices in one launch (bf16 out, BK=64 pairs, XCD swz)
  sim_gemm_pair2<<<dim3(18, 18, 4), 256, 0, stream>>>(ikT, pkT, keyT, simG, simL);

  // matching scores (rowstats, then both score passes in one launch)
  rowstats<<<dim3(2 * 2304), 256, 0, stream>>>(simL, cutv, mnv);
  score_both<<<dim3(9, 18, 4), 256, 0, stream>>>(simG, simL, init_seg, prev_seg,
      cutv, mnv, msc);

  // stage 1
  conv1x1_bk64<64><<<dim3(36, 4, 2), 256, 0, stream>>>(feats_s16, wc1b, b_conv1, x1, 1024, 48, 544);
  fillmask<<<dim3(2048), 256, 0, stream>>>(msc, mask_f, x1);
  blend3x3_bk64<48, 64><<<dim3(36, 4, 2), 256, 0, stream>>>(x1, wr1, b_blend1, b1o, 544);

  // stage 2: conv2 + deconv1 merged (deconv1 reads b1o, writes x2 ch256..257)
  conv1x1_dec<128, 48><<<dim3(144 + 38, 2, 2), 256, 0, stream>>>(
      feats_s8, wc2b, b_conv2, x2, 512, 96, 288,
      b1o, wd1r, b_dec1, x2, 144);
  blend3x3_bk64<96, 128><<<dim3(144, 2, 2), 256, 0, stream>>>(x2, wr2, b_blend2, b2o, 288);

  // stage 3: conv3 + deconv2 merged (deconv2 reads b2o, writes x3 ch256..257)
  conv1x1_dec<128, 96><<<dim3(576 + 148, 2, 2), 256, 0, stream>>>(
      feats_s4, wc3b, b_conv3, x3, 256, 192, 288,
      b2o, wd2r, b_dec2, x3, 576);
  blend3x3_bk64<192, 128><<<dim3(576, 2, 2), 256, 0, stream>>>(x3, wr3, b_blend3, b3o, 288);
  deconv_dir<4, 192, 2, true><<<dim3((193 * 193 + 63) / 64, 2), 256, 0, stream>>>(
      b3o, wd3r, b_dec3, d_out, 2, 0);
}